// Round 1
// baseline (297.867 us; speedup 1.0000x reference)
//
#include <hip/hip_runtime.h>

#define D      128
#define S      10
#define ROWS   64
#define HS     260          // padded LDS row stride (2D=256, +4 keeps 16B align, breaks bank aliasing)
#define BLOCK  256

__global__ __launch_bounds__(BLOCK, 2) void sage_kernel(
    const int* __restrict__ batch, const int* __restrict__ neigh,
    const float* __restrict__ Z, const float* __restrict__ W,
    float* __restrict__ out, int B)
{
    __shared__ float Hs[ROWS * HS];       // 66,560 B
    __shared__ int   sb[ROWS];
    __shared__ int   sn[ROWS * S];

    const int tid  = threadIdx.x;
    const int base = blockIdx.x * ROWS;
    const int rows = min(ROWS, B - base);

    // ---- stage indices ----
    for (int x = tid; x < rows; x += BLOCK)     sb[x] = batch[base + x];
    for (int x = tid; x < rows * S; x += BLOCK) sn[x] = neigh[base * S + x];
    __syncthreads();

    // ---- gather + mean-aggregate into Hs = [self(128) | mean(128)] ----
    #pragma unroll
    for (int w = 0; w < (ROWS * 32) / BLOCK; ++w) {
        const int task = w * BLOCK + tid;
        const int r = task >> 5;          // row within block
        const int c = task & 31;          // float4 chunk within row (32 * 4 = 128)
        if (r < rows) {
            const float4* zs = (const float4*)(Z + (size_t)sb[r] * D);
            const float4 sv = zs[c];
            float ax = 0.f, ay = 0.f, az = 0.f, aw = 0.f;
            #pragma unroll
            for (int s = 0; s < S; ++s) {
                const float4* zn = (const float4*)(Z + (size_t)sn[r * S + s] * D);
                const float4 v = zn[c];
                ax += v.x; ay += v.y; az += v.z; aw += v.w;
            }
            *(float4*)&Hs[r * HS + c * 4] = sv;
            float4 m; m.x = ax * 0.1f; m.y = ay * 0.1f; m.z = az * 0.1f; m.w = aw * 0.1f;
            *(float4*)&Hs[r * HS + D + c * 4] = m;
        } else {
            const float4 zz = {0.f, 0.f, 0.f, 0.f};
            *(float4*)&Hs[r * HS + c * 4] = zz;
            *(float4*)&Hs[r * HS + D + c * 4] = zz;
        }
    }
    __syncthreads();

    // ---- GEMM: out[r][j] = sigmoid( sum_k Hs[r][k] * W[j][k] ), then L2-normalize ----
    const int jg = tid & 31;              // 32 column groups
    const int rg = tid >> 5;              // 8 row groups
    const int j0 = jg * 4;                // 4 consecutive output cols per thread

    float acc[8][4];
    #pragma unroll
    for (int i = 0; i < 8; ++i)
        #pragma unroll
        for (int j = 0; j < 4; ++j) acc[i][j] = 0.f;

    for (int k4 = 0; k4 < (2 * D) / 4; ++k4) {
        const int k = k4 * 4;
        float4 wv[4];
        #pragma unroll
        for (int ji = 0; ji < 4; ++ji)
            wv[ji] = *(const float4*)(W + (size_t)(j0 + ji) * (2 * D) + k);
        #pragma unroll
        for (int ri = 0; ri < 8; ++ri) {
            const float4 hv = *(const float4*)&Hs[(rg * 8 + ri) * HS + k];
            #pragma unroll
            for (int ji = 0; ji < 4; ++ji)
                acc[ri][ji] += hv.x * wv[ji].x + hv.y * wv[ji].y
                             + hv.z * wv[ji].z + hv.w * wv[ji].w;
        }
    }

    // ---- epilogue: sigmoid -> row sum of squares (32-lane reduce) -> normalize -> store ----
    #pragma unroll
    for (int ri = 0; ri < 8; ++ri) {
        const int r = rg * 8 + ri;
        float z[4], ss = 0.f;
        #pragma unroll
        for (int ji = 0; ji < 4; ++ji) {
            z[ji] = 1.0f / (1.0f + __expf(-acc[ri][ji]));
            ss += z[ji] * z[ji];
        }
        #pragma unroll
        for (int m = 16; m >= 1; m >>= 1)
            ss += __shfl_xor(ss, m, 32);
        const float rn = rsqrtf(ss);
        if (r < rows) {
            float4 o; o.x = z[0] * rn; o.y = z[1] * rn; o.z = z[2] * rn; o.w = z[3] * rn;
            *(float4*)(out + (size_t)(base + r) * D + j0) = o;
        }
    }
}

extern "C" void kernel_launch(void* const* d_in, const int* in_sizes, int n_in,
                              void* d_out, int out_size, void* d_ws, size_t ws_size,
                              hipStream_t stream) {
    const int*   batch = (const int*)d_in[0];
    const int*   neigh = (const int*)d_in[1];
    const float* Z     = (const float*)d_in[2];
    const float* W     = (const float*)d_in[3];
    float*       out   = (float*)d_out;
    const int B = in_sizes[0];

    const int grid = (B + ROWS - 1) / ROWS;
    hipLaunchKernelGGL(sage_kernel, dim3(grid), dim3(BLOCK), 0, stream,
                       batch, neigh, Z, W, out, B);
}